// Round 11
// baseline (1809.428 us; speedup 1.0000x reference)
//
#include <hip/hip_runtime.h>
#include <hip/hip_bf16.h>

#define NB 128
#define LSEQ 512
#define HD 512
#define NI (NB * LSEQ)
#define MAX_DEPTH 40
#define SLICES 32
#define GRPS 8
#define MTILE 512

typedef __attribute__((ext_vector_type(8))) short bf16x8;
typedef __attribute__((ext_vector_type(4))) float f32x4;

static __device__ __forceinline__ unsigned f2b(float x) {
    union { __hip_bfloat16 b; unsigned short u; } cv;
    cv.b = __float2bfloat16(x);
    return (unsigned)cv.u;
}
static __device__ __forceinline__ float b2f(unsigned short u) {
    union { __hip_bfloat16 b; unsigned short u; } cv;
    cv.u = u;
    return __bfloat162float(cv.b);
}

// ---------------------------------------------------------------------------
// setup: h0 -> bf16, zero page, zero counts/cursor (re-zeroed every call so
// graph replays are deterministic)
// ---------------------------------------------------------------------------
__global__ __launch_bounds__(256) void setup_kernel(
    const float* __restrict__ h0,
    unsigned short* __restrict__ h0bf, unsigned short* __restrict__ zeropage,
    int* __restrict__ counts, int* __restrict__ cursor)
{
    int i = blockIdx.x * 256 + threadIdx.x;
    if (i < NB * HD) h0bf[i] = (unsigned short)f2b(h0[i]);
    if (i < 1024) zeropage[i] = 0;
    if (i < LSEQ) { counts[i] = 0; cursor[i] = 0; }
}

// ---------------------------------------------------------------------------
// pack: W [1536][512] row-major -> MFMA-B-frag-major bf16.
// lane l of frag (ct,kc) holds B[k=kc*32+(l>>4)*8+j][col=ct*16+(l&15)], j=0..7
// element index: ((ct*16+kc)*64 + lane)*8 + j ; ct = global col/16 (0..95)
// ---------------------------------------------------------------------------
__global__ __launch_bounds__(256) void pack_kernel(
    const float* __restrict__ W_ih, const float* __restrict__ W_hh,
    unsigned short* __restrict__ Xpack, unsigned short* __restrict__ Hpack)
{
    int idx = blockIdx.x * 256 + threadIdx.x;   // = g*512 + k
    if (idx >= 1536 * 512) return;
    int g = idx >> 9, k = idx & 511;
    int ct = g >> 4, lane_lo = g & 15;
    int kc = k >> 5, kin = k & 31;
    int lane = (kin >> 3) * 16 + lane_lo;
    int j = kin & 7;
    int p = ((ct * 16 + kc) * 64 + lane) * 8 + j;
    Xpack[p] = (unsigned short)f2b(W_ih[idx]);
    Hpack[p] = (unsigned short)f2b(W_hh[idx]);
}

// ---------------------------------------------------------------------------
// xcvt: inp f32 -> xbf bf16 (natural order), 8 elems/thread
// ---------------------------------------------------------------------------
__global__ __launch_bounds__(256) void xcvt_kernel(
    const float* __restrict__ inp, unsigned short* __restrict__ xbf)
{
    size_t i = ((size_t)blockIdx.x * 256 + threadIdx.x) * 8;
    float4 v0 = *(const float4*)(inp + i);
    float4 v1 = *(const float4*)(inp + i + 4);
    uint4 u;
    u.x = f2b(v0.x) | (f2b(v0.y) << 16);
    u.y = f2b(v0.z) | (f2b(v0.w) << 16);
    u.z = f2b(v1.x) | (f2b(v1.y) << 16);
    u.w = f2b(v1.z) | (f2b(v1.w) << 16);
    *(uint4*)(xbf + i) = u;
}

// ---------------------------------------------------------------------------
// sched1: per-row depth via inclusive max-scan over last-reset position.
// d(n,l) = l - max{l' <= l : is_init(n,l') or l'==0}
// ---------------------------------------------------------------------------
__global__ __launch_bounds__(512) void sched1_kernel(
    const int* __restrict__ is_init,
    int* __restrict__ d_of, int* __restrict__ counts)
{
    __shared__ int s[LSEQ];
    int n = blockIdx.x, l = threadIdx.x;
    int ii = is_init[n * LSEQ + l];
    s[l] = ii ? l : 0;
    __syncthreads();
    #pragma unroll
    for (int off = 1; off < LSEQ; off <<= 1) {
        int v = (l >= off) ? s[l - off] : 0;
        __syncthreads();
        if (v > s[l]) s[l] = v;
        __syncthreads();
    }
    int d = l - s[l];
    d_of[n * LSEQ + l] = d;
    atomicAdd(&counts[d], 1);
}

// ---------------------------------------------------------------------------
// sched2: exclusive-scan counts -> offsets
// ---------------------------------------------------------------------------
__global__ __launch_bounds__(512) void sched2_kernel(
    const int* __restrict__ counts, int* __restrict__ offsets)
{
    __shared__ int s[LSEQ];
    int l = threadIdx.x;
    int c = counts[l];
    s[l] = c;
    __syncthreads();
    #pragma unroll
    for (int off = 1; off < LSEQ; off <<= 1) {
        int v = (l >= off) ? s[l - off] : 0;
        __syncthreads();
        s[l] += v;
        __syncthreads();
    }
    offsets[l] = s[l] - c;
}

// ---------------------------------------------------------------------------
// sched3: assign positions within depth buckets; pos_of + items
// ---------------------------------------------------------------------------
__global__ __launch_bounds__(512) void sched3_kernel(
    const int* __restrict__ d_of, const int* __restrict__ offsets,
    int* __restrict__ cursor, int* __restrict__ pos_of, int* __restrict__ items)
{
    int i = blockIdx.x * 512 + threadIdx.x;
    int d = d_of[i];
    int pos = offsets[d] + atomicAdd(&cursor[d], 1);
    pos_of[i] = pos;
    items[pos] = i;
}

// ---------------------------------------------------------------------------
// sched4: prevoff[pos] = prev hperm elem offset | -1 (zero) | -(n*512+2) (h0)
// ---------------------------------------------------------------------------
__global__ __launch_bounds__(512) void sched4_kernel(
    const int* __restrict__ is_init, const int* __restrict__ d_of,
    const int* __restrict__ pos_of, int* __restrict__ prevoff)
{
    int i = blockIdx.x * 512 + threadIdx.x;
    int d = d_of[i];
    int pos = pos_of[i];
    int pr;
    if (d == 0) pr = is_init[i] ? -1 : -((i >> 9) * 512 + 2);
    else pr = pos_of[i - 1] * 512;
    prevoff[pos] = pr;
}

// ---------------------------------------------------------------------------
// fphase: FUSED depth-d GRU step: gates = x@W_ih^T + h@W_hh^T + b, both
// weight slices LDS-resident (96 KB -> 1 block/CU, 8 waves).
// Grid 256 = 32 slices x 8 grps; bid%8 = grp so all 32 slices of a tile-group
// hit one XCD's L2 for the x/hprev row gathers.
// Per wave: 4 item-frags (64 items) x 1 col-frag per gate -> 12 MFMA per
// 3 ds_read_b128 (LDS-BW ratio 2x better than round 9). MTILE = 8w*64 = 512.
// Blocks with grp >= ntiles exit before the weight load (free empty launches).
// ---------------------------------------------------------------------------
__global__ __launch_bounds__(512, 2) void fphase_kernel(
    int d,
    const unsigned short* __restrict__ Xpack, const unsigned short* __restrict__ Hpack,
    const float* __restrict__ b_ih, const float* __restrict__ b_hh,
    const int* __restrict__ counts, const int* __restrict__ offsets,
    const int* __restrict__ prevoff, const int* __restrict__ items,
    const unsigned short* __restrict__ xbf,
    const unsigned short* __restrict__ h0bf, const unsigned short* __restrict__ zeropage,
    unsigned short* __restrict__ hperm)
{
    const int count = counts[d];
    const int slice = blockIdx.x >> 3;
    const int grp = blockIdx.x & 7;
    const int ntiles = (count + MTILE - 1) >> 9;
    if (grp >= ntiles) return;
    const int base = offsets[d];
    const int tid = threadIdx.x;
    const int w = tid >> 6, lane = tid & 63;
    const int l15 = lane & 15, lhi = lane >> 4;

    __shared__ unsigned short Wl[6 * 16 * 512];   // 96 KB: [0..2]=Wih, [3..5]=Whh

    // load both weight slices (each gate-ct = 16 KB = 1024 uint4)
    #pragma unroll
    for (int i = 0; i < 12; ++i) {
        int q = tid + i * 512;            // uint4 index, 6144 total
        int g = q >> 10, rem = q & 1023;
        const unsigned short* src = (g < 3)
            ? (Xpack + (size_t)(g * 32 + slice) * 8192)
            : (Hpack + (size_t)((g - 3) * 32 + slice) * 8192);
        ((uint4*)Wl)[q] = *((const uint4*)src + rem);
    }
    // per-lane biases (each lane owns exactly one column per gate)
    const int col = slice * 16 + l15;
    const float bR = b_ih[col] + b_hh[col];
    const float bZ = b_ih[512 + col] + b_hh[512 + col];
    const float bNX = b_ih[1024 + col];
    const float bNH = b_hh[1024 + col];
    __syncthreads();

    for (int tile = grp; tile < ntiles; tile += GRPS) {
        // per-lane A-row pointers (4 item-frags; row = ... + l15)
        const unsigned short* xp[4];
        const unsigned short* hp[4];
        #pragma unroll
        for (int f = 0; f < 4; ++f) {
            int row = tile * MTILE + w * 64 + f * 16 + l15;
            if (row < count) {
                xp[f] = xbf + (size_t)items[base + row] * 512;
                int off = prevoff[base + row];
                hp[f] = (off >= 0) ? (hperm + off)
                      : (off == -1 ? zeropage : (h0bf + (-off - 2)));
            } else {
                xp[f] = zeropage; hp[f] = zeropage;
            }
        }

        f32x4 aR[4], aZ[4], aNX[4], aNH[4];
        #pragma unroll
        for (int f = 0; f < 4; ++f) {
            aR[f]  = (f32x4){bR, bR, bR, bR};
            aZ[f]  = (f32x4){bZ, bZ, bZ, bZ};
            aNX[f] = (f32x4){bNX, bNX, bNX, bNX};
            aNH[f] = (f32x4){bNH, bNH, bNH, bNH};
        }

        // x half: accumulate R, Z, NX
        #pragma unroll 4
        for (int ks = 0; ks < 16; ++ks) {
            bf16x8 bRv = *(const bf16x8*)(Wl + (0 * 16 + ks) * 512 + lane * 8);
            bf16x8 bZv = *(const bf16x8*)(Wl + (1 * 16 + ks) * 512 + lane * 8);
            bf16x8 bNv = *(const bf16x8*)(Wl + (2 * 16 + ks) * 512 + lane * 8);
            #pragma unroll
            for (int f = 0; f < 4; ++f) {
                bf16x8 a = *(const bf16x8*)(xp[f] + lhi * 8 + ks * 32);
                aR[f]  = __builtin_amdgcn_mfma_f32_16x16x32_bf16(a, bRv, aR[f], 0, 0, 0);
                aZ[f]  = __builtin_amdgcn_mfma_f32_16x16x32_bf16(a, bZv, aZ[f], 0, 0, 0);
                aNX[f] = __builtin_amdgcn_mfma_f32_16x16x32_bf16(a, bNv, aNX[f], 0, 0, 0);
            }
        }
        // h half: accumulate R, Z, NH
        #pragma unroll 4
        for (int ks = 0; ks < 16; ++ks) {
            bf16x8 bRv = *(const bf16x8*)(Wl + (3 * 16 + ks) * 512 + lane * 8);
            bf16x8 bZv = *(const bf16x8*)(Wl + (4 * 16 + ks) * 512 + lane * 8);
            bf16x8 bNv = *(const bf16x8*)(Wl + (5 * 16 + ks) * 512 + lane * 8);
            #pragma unroll
            for (int f = 0; f < 4; ++f) {
                bf16x8 a = *(const bf16x8*)(hp[f] + lhi * 8 + ks * 32);
                aR[f]  = __builtin_amdgcn_mfma_f32_16x16x32_bf16(a, bRv, aR[f], 0, 0, 0);
                aZ[f]  = __builtin_amdgcn_mfma_f32_16x16x32_bf16(a, bZv, aZ[f], 0, 0, 0);
                aNH[f] = __builtin_amdgcn_mfma_f32_16x16x32_bf16(a, bNv, aNH[f], 0, 0, 0);
            }
        }

        // epilogue: GRU pointwise (C/D: item=(lane>>4)*4+v, col=lane&15)
        #pragma unroll
        for (int f = 0; f < 4; ++f) {
            #pragma unroll
            for (int v = 0; v < 4; ++v) {
                int row = tile * MTILE + w * 64 + f * 16 + lhi * 4 + v;
                if (row >= count) continue;
                size_t pos = (size_t)(base + row);
                int off = prevoff[pos];
                const unsigned short* hpp = (off >= 0) ? (hperm + off)
                    : (off == -1 ? zeropage : (h0bf + (-off - 2)));
                float hprev = b2f(hpp[col]);
                float r = 1.f / (1.f + __expf(-aR[f][v]));
                float z = 1.f / (1.f + __expf(-aZ[f][v]));
                float nn = tanhf(aNX[f][v] + r * aNH[f][v]);
                hperm[pos * 512 + col] = (unsigned short)f2b((1.f - z) * nn + z * hprev);
            }
        }
    }
}

// ---------------------------------------------------------------------------
// hlast: h[n, L-1, :] -> fp32 ws (via pos_of; before hexp overwrites hperm)
// ---------------------------------------------------------------------------
__global__ __launch_bounds__(256) void hlast_kernel(
    const unsigned short* __restrict__ hperm, const int* __restrict__ pos_of,
    float* __restrict__ hlast)
{
    int i = blockIdx.x * 256 + threadIdx.x;
    if (i >= NB * HD) return;
    int n = i >> 9, c = i & 511;
    size_t pos = (size_t)pos_of[n * LSEQ + (LSEQ - 1)];
    hlast[i] = b2f(hperm[pos * HD + c]);
}

// ---------------------------------------------------------------------------
// LayerNorm: out1[n,l] = LN(hperm[pos_of[n,l]] + inp[n,l]) * gamma + beta
// ---------------------------------------------------------------------------
__global__ __launch_bounds__(256) void ln_kernel(
    const unsigned short* __restrict__ hperm, const int* __restrict__ pos_of,
    const float* __restrict__ inp,
    const float* __restrict__ gamma, const float* __restrict__ beta,
    float* __restrict__ out1)
{
    size_t row = blockIdx.x;
    int tid = threadIdx.x;
    int c = tid * 2;
    size_t pos = (size_t)pos_of[row];
    const unsigned short* yrow = hperm + pos * HD;
    const float* xrow = inp + row * HD;
    ushort2 yv = *(const ushort2*)(yrow + c);
    float2 xv = *(const float2*)(xrow + c);
    float a = b2f(yv.x) + xv.x;
    float b = b2f(yv.y) + xv.y;
    float s = a + b, ss = a * a + b * b;
    #pragma unroll
    for (int m = 1; m < 64; m <<= 1) {
        s  += __shfl_xor(s, m, 64);
        ss += __shfl_xor(ss, m, 64);
    }
    __shared__ float ps[4], pss[4];
    int w = tid >> 6;
    if ((tid & 63) == 0) { ps[w] = s; pss[w] = ss; }
    __syncthreads();
    s  = ps[0] + ps[1] + ps[2] + ps[3];
    ss = pss[0] + pss[1] + pss[2] + pss[3];
    float mu = s * (1.f / 512.f);
    float var = ss * (1.f / 512.f) - mu * mu;
    float inv = rsqrtf(var + 1e-5f);
    float2 gv = *(const float2*)(gamma + c);
    float2 bv = *(const float2*)(beta + c);
    float2 o;
    o.x = (a - mu) * inv * gv.x + bv.x;
    o.y = (b - mu) * inv * gv.y + bv.y;
    *(float2*)(out1 + row * HD + c) = o;
}

// ---------------------------------------------------------------------------
// hexp: out2[n,l,:] = hlast[n,:]  (overwrites hperm region; runs last)
// ---------------------------------------------------------------------------
__global__ __launch_bounds__(256) void hexp_kernel(
    const float* __restrict__ hlast, float* __restrict__ out2)
{
    size_t idx = (size_t)blockIdx.x * 256 + threadIdx.x;   // float4 units
    if (idx >= (size_t)NI * HD / 4) return;
    int per_n = LSEQ * HD / 4;
    int n = (int)(idx / per_n);
    int c4 = (int)(idx & (HD / 4 - 1));
    float4 v = *(const float4*)(hlast + n * HD + c4 * 4);
    *(float4*)(out2 + idx * 4) = v;
}

// ---------------------------------------------------------------------------
extern "C" void kernel_launch(void* const* d_in, const int* in_sizes, int n_in,
                              void* d_out, int out_size, void* d_ws, size_t ws_size,
                              hipStream_t stream)
{
    const float* inp   = (const float*)d_in[0];
    const float* h0    = (const float*)d_in[1];
    const int*  is_ini = (const int*)d_in[2];
    const float* W_ih  = (const float*)d_in[3];
    const float* W_hh  = (const float*)d_in[4];
    const float* b_ih  = (const float*)d_in[5];
    const float* b_hh  = (const float*)d_in[6];
    const float* gamma = (const float*)d_in[7];
    const float* beta  = (const float*)d_in[8];

    const size_t NLH = (size_t)NI * HD;            // 33,554,432
    float* out1 = (float*)d_out;
    float* out2 = out1 + NLH;
    // d_out overlay (268.4 MB):
    //   xbf   bf16 [NI][512] =  67.1 MB at offset 0     (dead before ln writes out1)
    //   hperm bf16 [NI][512] =  67.1 MB at offset 201.3 (dead after hlast/ln; hexp last)
    unsigned short* xbf   = (unsigned short*)d_out;
    unsigned short* hperm = (unsigned short*)d_out + (size_t)NI * 1536;

    unsigned short* Xpack = (unsigned short*)d_ws;            // 1.5 MB
    unsigned short* Hpack = Xpack + 1536 * 512;               // 1.5 MB
    int* counts  = (int*)(Hpack + 1536 * 512);                // 2 KB
    int* offsets = counts + LSEQ;                             // 2 KB
    int* cursor  = offsets + LSEQ;                            // 2 KB
    int* items   = cursor + LSEQ;                             // 256 KB
    int* pos_of  = items + NI;                                // 256 KB
    int* prevoff = pos_of + NI;                               // 256 KB
    int* d_of    = prevoff + NI;                              // 256 KB
    unsigned short* h0bf = (unsigned short*)(d_of + NI);      // 128 KB
    unsigned short* zeropage = h0bf + NB * HD;                // 2 KB
    float* hlast = (float*)(zeropage + 1024);                 // 256 KB

    setup_kernel<<<(NB * HD + 255) / 256, 256, 0, stream>>>(
        h0, h0bf, zeropage, counts, cursor);
    pack_kernel<<<(1536 * 512 + 255) / 256, 256, 0, stream>>>(W_ih, W_hh, Xpack, Hpack);
    xcvt_kernel<<<(int)(NLH / 8 / 256), 256, 0, stream>>>(inp, xbf);

    sched1_kernel<<<NB, 512, 0, stream>>>(is_ini, d_of, counts);
    sched2_kernel<<<1, 512, 0, stream>>>(counts, offsets);
    sched3_kernel<<<NI / 512, 512, 0, stream>>>(d_of, offsets, cursor, pos_of, items);
    sched4_kernel<<<NI / 512, 512, 0, stream>>>(is_ini, d_of, pos_of, prevoff);

    for (int d = 0; d < MAX_DEPTH; d++) {
        fphase_kernel<<<SLICES * GRPS, 512, 0, stream>>>(
            d, Xpack, Hpack, b_ih, b_hh, counts, offsets, prevoff, items,
            xbf, h0bf, zeropage, hperm);
    }

    hlast_kernel<<<(NB * HD + 255) / 256, 256, 0, stream>>>(hperm, pos_of, hlast);
    ln_kernel<<<NI, 256, 0, stream>>>(hperm, pos_of, inp, gamma, beta, out1);
    hexp_kernel<<<(int)(NLH / 4 / 256), 256, 0, stream>>>(hlast, out2);
}

// Round 12
// 1470.415 us; speedup vs baseline: 1.2306x; 1.2306x over previous
//
#include <hip/hip_runtime.h>
#include <hip/hip_bf16.h>

#define NB 128
#define LSEQ 512
#define HD 512
#define NI (NB * LSEQ)
#define MAX_DEPTH 40
#define SLICES 32
#define GRPS 16
#define MTILE 512

typedef __attribute__((ext_vector_type(8))) short bf16x8;
typedef __attribute__((ext_vector_type(4))) float f32x4;

static __device__ __forceinline__ unsigned f2b(float x) {
    union { __hip_bfloat16 b; unsigned short u; } cv;
    cv.b = __float2bfloat16(x);
    return (unsigned)cv.u;
}
static __device__ __forceinline__ float b2f(unsigned short u) {
    union { __hip_bfloat16 b; unsigned short u; } cv;
    cv.u = u;
    return __bfloat162float(cv.b);
}

// ---------------------------------------------------------------------------
// setup: h0 -> bf16, zero page
// ---------------------------------------------------------------------------
__global__ __launch_bounds__(256) void setup_kernel(
    const float* __restrict__ h0,
    unsigned short* __restrict__ h0bf, unsigned short* __restrict__ zeropage)
{
    int i = blockIdx.x * 256 + threadIdx.x;
    if (i < NB * HD) h0bf[i] = (unsigned short)f2b(h0[i]);
    if (i < 1024) zeropage[i] = 0;
}

// ---------------------------------------------------------------------------
// pack: W [1536][512] row-major -> MFMA-B-frag-major bf16.
// lane l of frag (ct,kc) holds B[k=kc*32+(l>>4)*8+j][col=ct*16+(l&15)], j=0..7
// element index: ((ct*16+kc)*64 + lane)*8 + j ; ct = global col/16 (0..95)
// ---------------------------------------------------------------------------
__global__ __launch_bounds__(256) void pack_kernel(
    const float* __restrict__ W_ih, const float* __restrict__ W_hh,
    unsigned short* __restrict__ Xpack, unsigned short* __restrict__ Hpack)
{
    int idx = blockIdx.x * 256 + threadIdx.x;   // = g*512 + k
    if (idx >= 1536 * 512) return;
    int g = idx >> 9, k = idx & 511;
    int ct = g >> 4, lane_lo = g & 15;
    int kc = k >> 5, kin = k & 31;
    int lane = (kin >> 3) * 16 + lane_lo;
    int j = kin & 7;
    int p = ((ct * 16 + kc) * 64 + lane) * 8 + j;
    Xpack[p] = (unsigned short)f2b(W_ih[idx]);
    Hpack[p] = (unsigned short)f2b(W_hh[idx]);
}

// ---------------------------------------------------------------------------
// sched: serial per-row scan (proven r6-r9; LDS atomics only).
//   counts/offsets per depth; pos_of[n*L+l]; prevoff[pos] = prev hperm elem
//   offset (>=0) | -1 (zero h) | -(n*512+2) (h0 row n)
// ---------------------------------------------------------------------------
__global__ __launch_bounds__(128) void sched_kernel(
    const int* __restrict__ is_init,
    int* __restrict__ counts_g, int* __restrict__ offsets_g,
    int* __restrict__ pos_of, int* __restrict__ prevoff)
{
    __shared__ int cnt[LSEQ];
    __shared__ int off[LSEQ];
    int tid = threadIdx.x;
    for (int i = tid; i < LSEQ; i += 128) cnt[i] = 0;
    __syncthreads();
    {
        int d = 0;
        for (int l = 0; l < LSEQ; l++) {
            int ii = is_init[tid * LSEQ + l];
            d = ii ? 0 : (l == 0 ? 0 : d + 1);
            atomicAdd(&cnt[d], 1);
        }
    }
    __syncthreads();
    if (tid == 0) {
        int acc = 0;
        for (int i = 0; i < LSEQ; i++) { off[i] = acc; acc += cnt[i]; }
    }
    __syncthreads();
    for (int i = tid; i < LSEQ; i += 128) {
        counts_g[i] = cnt[i];
        offsets_g[i] = off[i];
        cnt[i] = 0;
    }
    __syncthreads();
    {
        int d = 0;
        int prevpos = 0;
        for (int l = 0; l < LSEQ; l++) {
            int ii = is_init[tid * LSEQ + l];
            d = ii ? 0 : (l == 0 ? 0 : d + 1);
            int pos = off[d] + atomicAdd(&cnt[d], 1);
            pos_of[tid * LSEQ + l] = pos;
            int pr;
            if (d == 0) pr = ii ? -1 : -(tid * 512 + 2);
            else pr = prevpos * 512;
            prevoff[pos] = pr;
            prevpos = pos;
        }
    }
}

// ---------------------------------------------------------------------------
// xcvt: inp f32 -> xbf bf16 in POS ORDER (row i -> row pos_of[i]); phase
// x-reads become contiguous streams. 64 threads handle one row (8 elems each).
// ---------------------------------------------------------------------------
__global__ __launch_bounds__(256) void xcvt_kernel(
    const float* __restrict__ inp, const int* __restrict__ pos_of,
    unsigned short* __restrict__ xbf)
{
    size_t idx = (size_t)blockIdx.x * 256 + threadIdx.x;
    int row = (int)(idx >> 6);            // item index (n*L+l)
    int c8 = (int)(idx & 63);             // 8-elem chunk within row
    const float* src = inp + (size_t)row * 512 + c8 * 8;
    float4 v0 = *(const float4*)(src);
    float4 v1 = *(const float4*)(src + 4);
    uint4 u;
    u.x = f2b(v0.x) | (f2b(v0.y) << 16);
    u.y = f2b(v0.z) | (f2b(v0.w) << 16);
    u.z = f2b(v1.x) | (f2b(v1.y) << 16);
    u.w = f2b(v1.z) | (f2b(v1.w) << 16);
    size_t pos = (size_t)pos_of[row];
    *(uint4*)(xbf + pos * 512 + c8 * 8) = u;
}

// ---------------------------------------------------------------------------
// fphase: FUSED depth-d GRU step, LDS slice SWAP (48 KB, 2 blocks/CU):
//   per tile: load Xpack slice -> x-half MFMA (aR,aZ,aNX) ->
//             load Hpack slice -> h-half MFMA (aR,aZ,aNH) -> GRU epilogue.
// Grid 512 = 32 slices x 16 grps; bid%8 = grp%8 -> all 32 slices of a
// tile-group share one XCD's L2 (x stream + hprev gather are L2-local).
// Per wave: 4 item-frags x 1 col-frag/gate -> 12 MFMA : 3 ds_read_b128 : 4
// A-loads per k-step. MTILE = 8 waves * 64 = 512 items/tile.
// Blocks with grp >= ntiles exit before any LDS load (cheap tails).
// ---------------------------------------------------------------------------
__global__ __launch_bounds__(512, 4) void fphase_kernel(
    int d,
    const unsigned short* __restrict__ Xpack, const unsigned short* __restrict__ Hpack,
    const float* __restrict__ b_ih, const float* __restrict__ b_hh,
    const int* __restrict__ counts, const int* __restrict__ offsets,
    const int* __restrict__ prevoff,
    const unsigned short* __restrict__ xbf,
    const unsigned short* __restrict__ h0bf, const unsigned short* __restrict__ zeropage,
    unsigned short* __restrict__ hperm)
{
    const int count = counts[d];
    const int slice = blockIdx.x >> 4;
    const int grp = blockIdx.x & 15;
    const int ntiles = (count + MTILE - 1) >> 9;
    if (grp >= ntiles) return;
    const int base = offsets[d];
    const int tid = threadIdx.x;
    const int w = tid >> 6, lane = tid & 63;
    const int l15 = lane & 15, lhi = lane >> 4;

    __shared__ unsigned short Wl[3 * 16 * 512];   // 48 KB, swapped X<->H per tile

    const int col = slice * 16 + l15;
    const float bR = b_ih[col] + b_hh[col];
    const float bZ = b_ih[512 + col] + b_hh[512 + col];
    const float bNX = b_ih[1024 + col];
    const float bNH = b_hh[1024 + col];

    for (int tile = grp; tile < ntiles; tile += GRPS) {
        // per-lane A-row pointers (4 item-frags; row = ... + l15)
        const unsigned short* xp[4];
        const unsigned short* hp[4];
        #pragma unroll
        for (int f = 0; f < 4; ++f) {
            int row = tile * MTILE + w * 64 + f * 16 + l15;
            if (row < count) {
                xp[f] = xbf + (size_t)(base + row) * 512;      // contiguous (pos order)
                int off = prevoff[base + row];
                hp[f] = (off >= 0) ? (hperm + off)
                      : (off == -1 ? zeropage : (h0bf + (-off - 2)));
            } else {
                xp[f] = zeropage; hp[f] = zeropage;
            }
        }

        f32x4 aR[4], aZ[4], aNX[4], aNH[4];
        #pragma unroll
        for (int f = 0; f < 4; ++f) {
            aR[f]  = (f32x4){bR, bR, bR, bR};
            aZ[f]  = (f32x4){bZ, bZ, bZ, bZ};
            aNX[f] = (f32x4){bNX, bNX, bNX, bNX};
            aNH[f] = (f32x4){bNH, bNH, bNH, bNH};
        }

        // ---- X half ----
        __syncthreads();   // prior tile's H reads done
        #pragma unroll
        for (int i = 0; i < 6; ++i) {
            int q = tid + i * 512;        // uint4 index, 3072 total
            int g = q >> 10, rem = q & 1023;
            ((uint4*)Wl)[q] = *((const uint4*)(Xpack + (size_t)(g * 32 + slice) * 8192) + rem);
        }
        __syncthreads();
        #pragma unroll 4
        for (int ks = 0; ks < 16; ++ks) {
            bf16x8 bRv = *(const bf16x8*)(Wl + (0 * 16 + ks) * 512 + lane * 8);
            bf16x8 bZv = *(const bf16x8*)(Wl + (1 * 16 + ks) * 512 + lane * 8);
            bf16x8 bNv = *(const bf16x8*)(Wl + (2 * 16 + ks) * 512 + lane * 8);
            #pragma unroll
            for (int f = 0; f < 4; ++f) {
                bf16x8 a = *(const bf16x8*)(xp[f] + lhi * 8 + ks * 32);
                aR[f]  = __builtin_amdgcn_mfma_f32_16x16x32_bf16(a, bRv, aR[f], 0, 0, 0);
                aZ[f]  = __builtin_amdgcn_mfma_f32_16x16x32_bf16(a, bZv, aZ[f], 0, 0, 0);
                aNX[f] = __builtin_amdgcn_mfma_f32_16x16x32_bf16(a, bNv, aNX[f], 0, 0, 0);
            }
        }

        // ---- H half ----
        __syncthreads();   // X reads done
        #pragma unroll
        for (int i = 0; i < 6; ++i) {
            int q = tid + i * 512;
            int g = q >> 10, rem = q & 1023;
            ((uint4*)Wl)[q] = *((const uint4*)(Hpack + (size_t)(g * 32 + slice) * 8192) + rem);
        }
        __syncthreads();
        #pragma unroll 4
        for (int ks = 0; ks < 16; ++ks) {
            bf16x8 bRv = *(const bf16x8*)(Wl + (0 * 16 + ks) * 512 + lane * 8);
            bf16x8 bZv = *(const bf16x8*)(Wl + (1 * 16 + ks) * 512 + lane * 8);
            bf16x8 bNv = *(const bf16x8*)(Wl + (2 * 16 + ks) * 512 + lane * 8);
            #pragma unroll
            for (int f = 0; f < 4; ++f) {
                bf16x8 a = *(const bf16x8*)(hp[f] + lhi * 8 + ks * 32);
                aR[f]  = __builtin_amdgcn_mfma_f32_16x16x32_bf16(a, bRv, aR[f], 0, 0, 0);
                aZ[f]  = __builtin_amdgcn_mfma_f32_16x16x32_bf16(a, bZv, aZ[f], 0, 0, 0);
                aNH[f] = __builtin_amdgcn_mfma_f32_16x16x32_bf16(a, bNv, aNH[f], 0, 0, 0);
            }
        }

        // ---- epilogue: GRU pointwise (C/D: item=(lane>>4)*4+v, col=lane&15) ----
        #pragma unroll
        for (int f = 0; f < 4; ++f) {
            #pragma unroll
            for (int v = 0; v < 4; ++v) {
                int row = tile * MTILE + w * 64 + f * 16 + lhi * 4 + v;
                if (row >= count) continue;
                size_t pos = (size_t)(base + row);
                int off = prevoff[pos];
                const unsigned short* hpp = (off >= 0) ? (hperm + off)
                    : (off == -1 ? zeropage : (h0bf + (-off - 2)));
                float hprev = b2f(hpp[col]);
                float r = 1.f / (1.f + __expf(-aR[f][v]));
                float z = 1.f / (1.f + __expf(-aZ[f][v]));
                float nn = tanhf(aNX[f][v] + r * aNH[f][v]);
                hperm[pos * 512 + col] = (unsigned short)f2b((1.f - z) * nn + z * hprev);
            }
        }
    }
}

// ---------------------------------------------------------------------------
// hlast: h[n, L-1, :] -> fp32 ws (via pos_of; before hexp overwrites hperm)
// ---------------------------------------------------------------------------
__global__ __launch_bounds__(256) void hlast_kernel(
    const unsigned short* __restrict__ hperm, const int* __restrict__ pos_of,
    float* __restrict__ hlast)
{
    int i = blockIdx.x * 256 + threadIdx.x;
    if (i >= NB * HD) return;
    int n = i >> 9, c = i & 511;
    size_t pos = (size_t)pos_of[n * LSEQ + (LSEQ - 1)];
    hlast[i] = b2f(hperm[pos * HD + c]);
}

// ---------------------------------------------------------------------------
// LayerNorm: out1[n,l] = LN(hperm[pos_of[n,l]] + inp[n,l]) * gamma + beta
// ---------------------------------------------------------------------------
__global__ __launch_bounds__(256) void ln_kernel(
    const unsigned short* __restrict__ hperm, const int* __restrict__ pos_of,
    const float* __restrict__ inp,
    const float* __restrict__ gamma, const float* __restrict__ beta,
    float* __restrict__ out1)
{
    size_t row = blockIdx.x;
    int tid = threadIdx.x;
    int c = tid * 2;
    size_t pos = (size_t)pos_of[row];
    const unsigned short* yrow = hperm + pos * HD;
    const float* xrow = inp + row * HD;
    ushort2 yv = *(const ushort2*)(yrow + c);
    float2 xv = *(const float2*)(xrow + c);
    float a = b2f(yv.x) + xv.x;
    float b = b2f(yv.y) + xv.y;
    float s = a + b, ss = a * a + b * b;
    #pragma unroll
    for (int m = 1; m < 64; m <<= 1) {
        s  += __shfl_xor(s, m, 64);
        ss += __shfl_xor(ss, m, 64);
    }
    __shared__ float ps[4], pss[4];
    int w = tid >> 6;
    if ((tid & 63) == 0) { ps[w] = s; pss[w] = ss; }
    __syncthreads();
    s  = ps[0] + ps[1] + ps[2] + ps[3];
    ss = pss[0] + pss[1] + pss[2] + pss[3];
    float mu = s * (1.f / 512.f);
    float var = ss * (1.f / 512.f) - mu * mu;
    float inv = rsqrtf(var + 1e-5f);
    float2 gv = *(const float2*)(gamma + c);
    float2 bv = *(const float2*)(beta + c);
    float2 o;
    o.x = (a - mu) * inv * gv.x + bv.x;
    o.y = (b - mu) * inv * gv.y + bv.y;
    *(float2*)(out1 + row * HD + c) = o;
}

// ---------------------------------------------------------------------------
// hexp: out2[n,l,:] = hlast[n,:]  (overwrites hperm region; runs last)
// ---------------------------------------------------------------------------
__global__ __launch_bounds__(256) void hexp_kernel(
    const float* __restrict__ hlast, float* __restrict__ out2)
{
    size_t idx = (size_t)blockIdx.x * 256 + threadIdx.x;   // float4 units
    if (idx >= (size_t)NI * HD / 4) return;
    int per_n = LSEQ * HD / 4;
    int n = (int)(idx / per_n);
    int c4 = (int)(idx & (HD / 4 - 1));
    float4 v = *(const float4*)(hlast + n * HD + c4 * 4);
    *(float4*)(out2 + idx * 4) = v;
}

// ---------------------------------------------------------------------------
extern "C" void kernel_launch(void* const* d_in, const int* in_sizes, int n_in,
                              void* d_out, int out_size, void* d_ws, size_t ws_size,
                              hipStream_t stream)
{
    const float* inp   = (const float*)d_in[0];
    const float* h0    = (const float*)d_in[1];
    const int*  is_ini = (const int*)d_in[2];
    const float* W_ih  = (const float*)d_in[3];
    const float* W_hh  = (const float*)d_in[4];
    const float* b_ih  = (const float*)d_in[5];
    const float* b_hh  = (const float*)d_in[6];
    const float* gamma = (const float*)d_in[7];
    const float* beta  = (const float*)d_in[8];

    const size_t NLH = (size_t)NI * HD;            // 33,554,432
    float* out1 = (float*)d_out;
    float* out2 = out1 + NLH;
    // d_out overlay (268.4 MB):
    //   xbf   bf16 [NI][512] = 67.1 MB in out1 region (dead before ln writes out1)
    //   hperm bf16 [NI][512] = 67.1 MB in out2 region (dead after hlast/ln; hexp last)
    unsigned short* xbf   = (unsigned short*)out1;
    unsigned short* hperm = (unsigned short*)out2;

    unsigned short* Xpack = (unsigned short*)d_ws;            // 1.5 MB
    unsigned short* Hpack = Xpack + 1536 * 512;               // 1.5 MB
    int* counts  = (int*)(Hpack + 1536 * 512);                // 2 KB
    int* offsets = counts + LSEQ;                             // 2 KB
    int* pos_of  = offsets + LSEQ;                            // 256 KB
    int* prevoff = pos_of + NI;                               // 256 KB
    unsigned short* h0bf = (unsigned short*)(prevoff + NI);   // 128 KB
    unsigned short* zeropage = h0bf + NB * HD;                // 2 KB
    float* hlast = (float*)(zeropage + 1024);                 // 256 KB

    setup_kernel<<<(NB * HD + 255) / 256, 256, 0, stream>>>(h0, h0bf, zeropage);
    pack_kernel<<<(1536 * 512 + 255) / 256, 256, 0, stream>>>(W_ih, W_hh, Xpack, Hpack);
    sched_kernel<<<1, 128, 0, stream>>>(is_ini, counts, offsets, pos_of, prevoff);

    xcvt_kernel<<<(int)(NLH / 8 / 256), 256, 0, stream>>>(inp, pos_of, xbf);

    for (int d = 0; d < MAX_DEPTH; d++) {
        fphase_kernel<<<SLICES * GRPS, 512, 0, stream>>>(
            d, Xpack, Hpack, b_ih, b_hh, counts, offsets, prevoff,
            xbf, h0bf, zeropage, hperm);
    }

    hlast_kernel<<<(NB * HD + 255) / 256, 256, 0, stream>>>(hperm, pos_of, hlast);
    ln_kernel<<<NI, 256, 0, stream>>>(hperm, pos_of, inp, gamma, beta, out1);
    hexp_kernel<<<(int)(NLH / 4 / 256), 256, 0, stream>>>(hlast, out2);
}